// Round 3
// baseline (1251.544 us; speedup 1.0000x reference)
//
#include <hip/hip_runtime.h>
#include <hip/hip_cooperative_groups.h>
#include <math.h>

#define NEG_INF (-INFINITY)

namespace cg = cooperative_groups;

typedef int      v4i __attribute__((ext_vector_type(4)));
typedef float    v4f __attribute__((ext_vector_type(4)));
typedef _Float16 v4h __attribute__((ext_vector_type(4)));

// fast log1mexp for v < 0: log(1 - e^v). Rel err ~1e-6.
__device__ __forceinline__ float fast_log1mexp(float v) {
    if (v > -0.125f) {
        float e = v * (1.0f + v * (0.5f + v * (0.16666667f + v * 0.041666667f)));
        return __logf(-e);
    }
    return __logf(1.0f - __expf(v));
}

// encoded-x ptr -> clamped index into wh
__device__ __forceinline__ int widx(int p) { int j = (p >> 1) - 1; return j < 0 ? 0 : j; }
// fixup a raw gathered weight per ptr parity/constants
__device__ __forceinline__ float fixw(int p, float v) {
    float r = (p & 1) ? fast_log1mexp(v) : v;
    if (p < 2) r = (p == 0) ? NEG_INF : 0.0f;
    return r;
}

// partial stable LSE (no epsilon): -inf if all inputs -inf.
__device__ __forceinline__ float plse4(float a, float b, float c, float d) {
    float m = fmaxf(fmaxf(a, b), fmaxf(c, d));
    if (m == NEG_INF) return NEG_INF;
    float s = __expf(a - m) + __expf(b - m) + __expf(c - m) + __expf(d - m);
    return __logf(s) + m;
}

// exact two-way LSE merge (epsilon once, matching ref)
__device__ __forceinline__ float merge_lse(float LA, float LB) {
    float m = fmaxf(LA, LB);
    if (m == NEG_INF) return NEG_INF;
    float s = __expf(LA - m) + __expf(LB - m) + 1e-15f;
    return __logf(s) + m;
}

// exact stable 4-way LSE with ref's epsilon
__device__ __forceinline__ float lse4(float a, float b, float c, float d) {
    float m = fmaxf(fmaxf(a, b), fmaxf(c, d));
    if (m == NEG_INF) return NEG_INF;
    float s = __expf(a - m) + __expf(b - m) + __expf(c - m) + __expf(d - m) + 1e-15f;
    return __logf(s) + m;
}

// Whole pipeline as ONE cooperative persistent kernel.
// grid.sync() replaces kernel boundaries: kills 4 launch gaps + 5 ramp/tails,
// and makes l1's two-phase 4MB-working-set split EXACT (grid-wide barrier
// between phase A and phase B instead of best-effort co-residency drift).
// launch_bounds(256,8) -> <=64 VGPR -> 2048 blocks fully co-resident.
__global__ __launch_bounds__(256, 8) void spn_mega_kernel(
    const float* __restrict__ w,
    _Float16* __restrict__ wh,
    const v4i* __restrict__ ptrs0,
    _Float16* __restrict__ y0,
    const v4i* __restrict__ ptrs1,
    _Float16* __restrict__ y1,
    const v4i* __restrict__ ptrs2,
    _Float16* __restrict__ y2,
    const v4i* __restrict__ ptrs3,
    float* __restrict__ out,
    int n_vars, int n0, int n1, int n2, int n3, int half0)
{
    cg::grid_group grid = cg::this_grid();
    const int tid = blockIdx.x * blockDim.x + threadIdx.x;
    const int NT  = gridDim.x * blockDim.x;

    // ---- cvt: w (fp32) -> wh (fp16) ----
    {
        int n4 = n_vars >> 2;
        for (int i = tid; i < n4; i += NT) {
            v4f v = reinterpret_cast<const v4f*>(w)[i];
            v4h o;
            o.x = (_Float16)v.x; o.y = (_Float16)v.y;
            o.z = (_Float16)v.z; o.w = (_Float16)v.w;
            reinterpret_cast<v4h*>(wh)[i] = o;
        }
        int base = n4 << 2;
        int rem = n_vars - base;
        if (tid < rem) wh[base + tid] = (_Float16)w[base + tid];
    }
    grid.sync();

    // ---- layer 0: product node fused with encode, 4 nodes/vthread ----
    {
        int h = (n0 + 3) >> 2;
        for (int t = tid; t < h; t += NT) {
            int i0 = t, i1 = t + h, i2 = t + 2 * h, i3 = t + 3 * h;
            int c1 = i1 < n0 ? i1 : 0, c2 = i2 < n0 ? i2 : 0, c3 = i3 < n0 ? i3 : 0;
            v4i p0 = __builtin_nontemporal_load(ptrs0 + i0);
            v4i p1 = __builtin_nontemporal_load(ptrs0 + c1);
            v4i p2 = __builtin_nontemporal_load(ptrs0 + c2);
            v4i p3 = __builtin_nontemporal_load(ptrs0 + c3);
            float g00 = (float)wh[widx(p0.x)], g01 = (float)wh[widx(p0.y)];
            float g02 = (float)wh[widx(p0.z)], g03 = (float)wh[widx(p0.w)];
            float g10 = (float)wh[widx(p1.x)], g11 = (float)wh[widx(p1.y)];
            float g12 = (float)wh[widx(p1.z)], g13 = (float)wh[widx(p1.w)];
            float g20 = (float)wh[widx(p2.x)], g21 = (float)wh[widx(p2.y)];
            float g22 = (float)wh[widx(p2.z)], g23 = (float)wh[widx(p2.w)];
            float g30 = (float)wh[widx(p3.x)], g31 = (float)wh[widx(p3.y)];
            float g32 = (float)wh[widx(p3.z)], g33 = (float)wh[widx(p3.w)];
            float s0 = (fixw(p0.x, g00) + fixw(p0.y, g01)) + (fixw(p0.z, g02) + fixw(p0.w, g03));
            float s1 = (fixw(p1.x, g10) + fixw(p1.y, g11)) + (fixw(p1.z, g12) + fixw(p1.w, g13));
            float s2 = (fixw(p2.x, g20) + fixw(p2.y, g21)) + (fixw(p2.z, g22) + fixw(p2.w, g23));
            float s3 = (fixw(p3.x, g30) + fixw(p3.y, g31)) + (fixw(p3.z, g32) + fixw(p3.w, g33));
            __builtin_nontemporal_store((_Float16)s0, y0 + i0);
            if (i1 < n0) __builtin_nontemporal_store((_Float16)s1, y0 + i1);
            if (i2 < n0) __builtin_nontemporal_store((_Float16)s2, y0 + i2);
            if (i3 < n0) __builtin_nontemporal_store((_Float16)s3, y0 + i3);
        }
    }
    grid.sync();

    // ---- layer 1: sum node, two-phase (lower/upper 4MB halves of y0),
    //      partials in registers, EXACT phase separation via grid.sync ----
    {
        int h = (n1 + 3) >> 2;
        int chunks = (h + NT - 1) / NT;   // uniform across grid
        for (int c = 0; c < chunks; ++c) {
            int vt = c * NT + tid;
            bool act = vt < h;
            int tt = act ? vt : 0;
            int i0 = tt, i1 = tt + h, i2 = tt + 2 * h, i3 = tt + 3 * h;
            int c1 = i1 < n1 ? i1 : 0, c2 = i2 < n1 ? i2 : 0, c3 = i3 < n1 ? i3 : 0;
            v4i p0 = __builtin_nontemporal_load(ptrs1 + i0);
            v4i p1 = __builtin_nontemporal_load(ptrs1 + c1);
            v4i p2 = __builtin_nontemporal_load(ptrs1 + c2);
            v4i p3 = __builtin_nontemporal_load(ptrs1 + c3);

            // phase A: lower half (4MB working set)
            float a0 = p0.x < half0 ? (float)y0[p0.x] : NEG_INF;
            float b0 = p0.y < half0 ? (float)y0[p0.y] : NEG_INF;
            float e0 = p0.z < half0 ? (float)y0[p0.z] : NEG_INF;
            float d0 = p0.w < half0 ? (float)y0[p0.w] : NEG_INF;
            float a1 = p1.x < half0 ? (float)y0[p1.x] : NEG_INF;
            float b1 = p1.y < half0 ? (float)y0[p1.y] : NEG_INF;
            float e1 = p1.z < half0 ? (float)y0[p1.z] : NEG_INF;
            float d1 = p1.w < half0 ? (float)y0[p1.w] : NEG_INF;
            float a2 = p2.x < half0 ? (float)y0[p2.x] : NEG_INF;
            float b2 = p2.y < half0 ? (float)y0[p2.y] : NEG_INF;
            float e2 = p2.z < half0 ? (float)y0[p2.z] : NEG_INF;
            float d2 = p2.w < half0 ? (float)y0[p2.w] : NEG_INF;
            float a3 = p3.x < half0 ? (float)y0[p3.x] : NEG_INF;
            float b3 = p3.y < half0 ? (float)y0[p3.y] : NEG_INF;
            float e3 = p3.z < half0 ? (float)y0[p3.z] : NEG_INF;
            float d3 = p3.w < half0 ? (float)y0[p3.w] : NEG_INF;
            float la0 = plse4(a0, b0, e0, d0);
            float la1 = plse4(a1, b1, e1, d1);
            float la2 = plse4(a2, b2, e2, d2);
            float la3 = plse4(a3, b3, e3, d3);

            grid.sync();  // exact working-set boundary

            // phase B: upper half + merge
            a0 = p0.x >= half0 ? (float)y0[p0.x] : NEG_INF;
            b0 = p0.y >= half0 ? (float)y0[p0.y] : NEG_INF;
            e0 = p0.z >= half0 ? (float)y0[p0.z] : NEG_INF;
            d0 = p0.w >= half0 ? (float)y0[p0.w] : NEG_INF;
            a1 = p1.x >= half0 ? (float)y0[p1.x] : NEG_INF;
            b1 = p1.y >= half0 ? (float)y0[p1.y] : NEG_INF;
            e1 = p1.z >= half0 ? (float)y0[p1.z] : NEG_INF;
            d1 = p1.w >= half0 ? (float)y0[p1.w] : NEG_INF;
            a2 = p2.x >= half0 ? (float)y0[p2.x] : NEG_INF;
            b2 = p2.y >= half0 ? (float)y0[p2.y] : NEG_INF;
            e2 = p2.z >= half0 ? (float)y0[p2.z] : NEG_INF;
            d2 = p2.w >= half0 ? (float)y0[p2.w] : NEG_INF;
            a3 = p3.x >= half0 ? (float)y0[p3.x] : NEG_INF;
            b3 = p3.y >= half0 ? (float)y0[p3.y] : NEG_INF;
            e3 = p3.z >= half0 ? (float)y0[p3.z] : NEG_INF;
            d3 = p3.w >= half0 ? (float)y0[p3.w] : NEG_INF;
            float s0 = merge_lse(la0, plse4(a0, b0, e0, d0));
            float s1 = merge_lse(la1, plse4(a1, b1, e1, d1));
            float s2 = merge_lse(la2, plse4(a2, b2, e2, d2));
            float s3 = merge_lse(la3, plse4(a3, b3, e3, d3));

            if (act) {
                __builtin_nontemporal_store((_Float16)s0, y1 + i0);
                if (i1 < n1) __builtin_nontemporal_store((_Float16)s1, y1 + i1);
                if (i2 < n1) __builtin_nontemporal_store((_Float16)s2, y1 + i2);
                if (i3 < n1) __builtin_nontemporal_store((_Float16)s3, y1 + i3);
            }
            grid.sync();  // l1 stores visible before l2 gathers (and next chunk)
        }
    }

    // ---- layer 2: product node, 2 nodes/vthread ----
    {
        int h = (n2 + 1) >> 1;
        for (int t = tid; t < h; t += NT) {
            int i0 = t, i1 = t + h;
            int c1 = i1 < n2 ? i1 : 0;
            v4i p0 = __builtin_nontemporal_load(ptrs2 + i0);
            v4i p1 = __builtin_nontemporal_load(ptrs2 + c1);
            float s0 = ((float)y1[p0.x] + (float)y1[p0.y]) + ((float)y1[p0.z] + (float)y1[p0.w]);
            float s1 = ((float)y1[p1.x] + (float)y1[p1.y]) + ((float)y1[p1.z] + (float)y1[p1.w]);
            __builtin_nontemporal_store((_Float16)s0, y2 + i0);
            if (i1 < n2) __builtin_nontemporal_store((_Float16)s1, y2 + i1);
        }
    }
    grid.sync();

    // ---- layer 3: final sum node, 1 node/vthread, fp32 out ----
    for (int t = tid; t < n3; t += NT) {
        v4i p = __builtin_nontemporal_load(ptrs3 + t);
        float r = lse4((float)y2[p.x], (float)y2[p.y], (float)y2[p.z], (float)y2[p.w]);
        __builtin_nontemporal_store(r, out + t);
    }
}

extern "C" void kernel_launch(void* const* d_in, const int* in_sizes, int n_in,
                              void* d_out, int out_size, void* d_ws, size_t ws_size,
                              hipStream_t stream) {
    // d_in dict order: weights, ptrs0, csr0, n0, ptrs1, csr1, n1, ptrs2, csr2, n2, ptrs3, csr3, n3
    const float* w     = (const float*)d_in[0];
    const v4i*   ptrs0 = (const v4i*)d_in[1];
    const v4i*   ptrs1 = (const v4i*)d_in[4];
    const v4i*   ptrs2 = (const v4i*)d_in[7];
    const v4i*   ptrs3 = (const v4i*)d_in[10];

    int n_vars = in_sizes[0];
    int n0 = in_sizes[1] / 4;
    int n1 = in_sizes[4] / 4;
    int n2 = in_sizes[7] / 4;
    int n3 = in_sizes[10] / 4;

    // workspace layout (256B-aligned), intermediates fp16
    char* ws = (char*)d_ws;
    size_t off = 0;
    _Float16* wh = (_Float16*)(ws + off); off += ((size_t)n_vars * 2 + 255) & ~(size_t)255;
    _Float16* y0 = (_Float16*)(ws + off); off += ((size_t)n0 * 2 + 255) & ~(size_t)255;
    _Float16* y1 = (_Float16*)(ws + off); off += ((size_t)n1 * 2 + 255) & ~(size_t)255;
    _Float16* y2 = (_Float16*)(ws + off);
    float* out = (float*)d_out;

    int half0 = n0 / 2;  // 4 MB fp16 boundary of y0

    // co-resident grid size (cached): blocks/CU from occupancy x CU count
    static int nblk = 0;
    if (nblk == 0) {
        int perCU = 0;
        if (hipOccupancyMaxActiveBlocksPerMultiprocessor(
                &perCU, reinterpret_cast<const void*>(spn_mega_kernel), 256, 0) != hipSuccess ||
            perCU <= 0)
            perCU = 8;
        int cus = 0;
        if (hipDeviceGetAttribute(&cus, hipDeviceAttributeMultiprocessorCount, 0) != hipSuccess ||
            cus <= 0)
            cus = 256;
        nblk = perCU * cus;
        if (nblk > 2048) nblk = 2048;
    }

    void* args[] = {
        (void*)&w, (void*)&wh,
        (void*)&ptrs0, (void*)&y0,
        (void*)&ptrs1, (void*)&y1,
        (void*)&ptrs2, (void*)&y2,
        (void*)&ptrs3, (void*)&out,
        (void*)&n_vars, (void*)&n0, (void*)&n1, (void*)&n2, (void*)&n3, (void*)&half0
    };
    hipLaunchCooperativeKernel(reinterpret_cast<const void*>(spn_mega_kernel),
                               dim3(nblk), dim3(256), args, 0, stream);
}

// Round 5
// 387.687 us; speedup vs baseline: 3.2282x; 3.2282x over previous
//
#include <hip/hip_runtime.h>
#include <math.h>

#define NEG_INF (-INFINITY)

typedef int      v4i __attribute__((ext_vector_type(4)));
typedef float    v4f __attribute__((ext_vector_type(4)));
typedef _Float16 v4h __attribute__((ext_vector_type(4)));
typedef _Float16 v2h __attribute__((ext_vector_type(2)));
typedef float    v2f __attribute__((ext_vector_type(2)));

// fast log1mexp for v < 0: log(1 - e^v). Rel err ~1e-6.
__device__ __forceinline__ float fast_log1mexp(float v) {
    if (v > -0.125f) {
        float e = v * (1.0f + v * (0.5f + v * (0.16666667f + v * 0.041666667f)));
        return __logf(-e);
    }
    return __logf(1.0f - __expf(v));
}

// w (fp32) -> wh (fp16)
__global__ __launch_bounds__(256) void cvt_kernel(const float* __restrict__ w,
                                                  _Float16* __restrict__ wh, int n) {
    int i = blockIdx.x * blockDim.x + threadIdx.x;
    int n4 = n >> 2;
    if (i < n4) {
        v4f v = reinterpret_cast<const v4f*>(w)[i];
        v4h o;
        o.x = (_Float16)v.x; o.y = (_Float16)v.y;
        o.z = (_Float16)v.z; o.w = (_Float16)v.w;
        reinterpret_cast<v4h*>(wh)[i] = o;
    }
    int base = n4 << 2;
    if (i < (n - base)) wh[base + i] = (_Float16)w[base + i];
}

// encoded-x ptr -> clamped index into wh
__device__ __forceinline__ int widx(int p) { int j = (p >> 1) - 1; return j < 0 ? 0 : j; }
// fixup a raw gathered weight per ptr parity/constants
__device__ __forceinline__ float fixw(int p, float v) {
    float r = (p & 1) ? fast_log1mexp(v) : v;
    if (p < 2) r = (p == 0) ? NEG_INF : 0.0f;
    return r;
}

// Layer 0: product node fused with encode. 4 CONSECUTIVE nodes/thread,
// single 8B merged store (was 4x2B): fewer VMEM issue slots, same bytes.
__global__ __launch_bounds__(256) void sum4_enc_kernel(const _Float16* __restrict__ wh,
                                                       const v4i* __restrict__ ptrs,
                                                       _Float16* __restrict__ y, int n, int h) {
    int t = blockIdx.x * blockDim.x + threadIdx.x;
    if (t >= h) return;
    int base = t << 2;
    int b1 = base + 1 < n ? base + 1 : 0;
    int b2 = base + 2 < n ? base + 2 : 0;
    int b3 = base + 3 < n ? base + 3 : 0;
    v4i p0 = __builtin_nontemporal_load(ptrs + base);
    v4i p1 = __builtin_nontemporal_load(ptrs + b1);
    v4i p2 = __builtin_nontemporal_load(ptrs + b2);
    v4i p3 = __builtin_nontemporal_load(ptrs + b3);
    float g00 = (float)wh[widx(p0.x)], g01 = (float)wh[widx(p0.y)];
    float g02 = (float)wh[widx(p0.z)], g03 = (float)wh[widx(p0.w)];
    float g10 = (float)wh[widx(p1.x)], g11 = (float)wh[widx(p1.y)];
    float g12 = (float)wh[widx(p1.z)], g13 = (float)wh[widx(p1.w)];
    float g20 = (float)wh[widx(p2.x)], g21 = (float)wh[widx(p2.y)];
    float g22 = (float)wh[widx(p2.z)], g23 = (float)wh[widx(p2.w)];
    float g30 = (float)wh[widx(p3.x)], g31 = (float)wh[widx(p3.y)];
    float g32 = (float)wh[widx(p3.z)], g33 = (float)wh[widx(p3.w)];
    float s0 = (fixw(p0.x, g00) + fixw(p0.y, g01)) + (fixw(p0.z, g02) + fixw(p0.w, g03));
    float s1 = (fixw(p1.x, g10) + fixw(p1.y, g11)) + (fixw(p1.z, g12) + fixw(p1.w, g13));
    float s2 = (fixw(p2.x, g20) + fixw(p2.y, g21)) + (fixw(p2.z, g22) + fixw(p2.w, g23));
    float s3 = (fixw(p3.x, g30) + fixw(p3.y, g31)) + (fixw(p3.z, g32) + fixw(p3.w, g33));
    if (base + 3 < n) {
        v4h o; o.x = (_Float16)s0; o.y = (_Float16)s1; o.z = (_Float16)s2; o.w = (_Float16)s3;
        __builtin_nontemporal_store(o, reinterpret_cast<v4h*>(y + base));
    } else {
        y[base] = (_Float16)s0;
        if (base + 1 < n) y[base + 1] = (_Float16)s1;
        if (base + 2 < n) y[base + 2] = (_Float16)s2;
    }
}

// partial stable LSE (no epsilon): -inf if all inputs -inf.
__device__ __forceinline__ float plse4(float a, float b, float c, float d) {
    float m = fmaxf(fmaxf(a, b), fmaxf(c, d));
    if (m == NEG_INF) return NEG_INF;
    float s = __expf(a - m) + __expf(b - m) + __expf(c - m) + __expf(d - m);
    return __logf(s) + m;
}

// exact two-way LSE merge (epsilon once, matching ref)
__device__ __forceinline__ float merge_lse(float LA, float LB) {
    float m = fmaxf(LA, LB);
    if (m == NEG_INF) return NEG_INF;
    float s = __expf(LA - m) + __expf(LB - m) + 1e-15f;
    return __logf(s) + m;
}

// address-clamp gather: NO exec-mask predication. Wrong-phase lanes read a
// single shared (cached) line, value replaced by -inf via cndmask.
// Converts 32 saveexec-guarded loads/thread into plain loads + selects.
__device__ __forceinline__ float gsel_lo(const _Float16* __restrict__ x, int p, int half) {
    int q = p < half ? p : 0;
    float v = (float)x[q];
    return p < half ? v : NEG_INF;
}
__device__ __forceinline__ float gsel_hi(const _Float16* __restrict__ x, int p, int half) {
    int q = p >= half ? p : half;
    float v = (float)x[q];
    return p >= half ? v : NEG_INF;
}

// Layer 1 (sum node): fused two-phase kernel, 4 consecutive nodes/thread,
// partial LSE carried in registers across the block-level phase aligner.
// Phase A working set = lower 4MB of y0 (per-XCD-L2-sized), phase B = upper.
__global__ __launch_bounds__(256) void l1_fused_kernel(const _Float16* __restrict__ x,
                                                       const v4i* __restrict__ ptrs,
                                                       _Float16* __restrict__ y,
                                                       int n, int h, int half) {
    int t = blockIdx.x * blockDim.x + threadIdx.x;
    bool act = t < h;
    int tt = act ? t : 0;
    int base = tt << 2;
    int b1 = base + 1 < n ? base + 1 : 0;
    int b2 = base + 2 < n ? base + 2 : 0;
    int b3 = base + 3 < n ? base + 3 : 0;
    v4i p0 = __builtin_nontemporal_load(ptrs + base);
    v4i p1 = __builtin_nontemporal_load(ptrs + b1);
    v4i p2 = __builtin_nontemporal_load(ptrs + b2);
    v4i p3 = __builtin_nontemporal_load(ptrs + b3);

    // phase A: lower-half working set
    float la0 = plse4(gsel_lo(x, p0.x, half), gsel_lo(x, p0.y, half),
                      gsel_lo(x, p0.z, half), gsel_lo(x, p0.w, half));
    float la1 = plse4(gsel_lo(x, p1.x, half), gsel_lo(x, p1.y, half),
                      gsel_lo(x, p1.z, half), gsel_lo(x, p1.w, half));
    float la2 = plse4(gsel_lo(x, p2.x, half), gsel_lo(x, p2.y, half),
                      gsel_lo(x, p2.z, half), gsel_lo(x, p2.w, half));
    float la3 = plse4(gsel_lo(x, p3.x, half), gsel_lo(x, p3.y, half),
                      gsel_lo(x, p3.z, half), gsel_lo(x, p3.w, half));

    __syncthreads();  // phase aligner: co-resident grid keeps working sets separated

    // phase B: upper-half working set + merge
    float s0 = merge_lse(la0, plse4(gsel_hi(x, p0.x, half), gsel_hi(x, p0.y, half),
                                    gsel_hi(x, p0.z, half), gsel_hi(x, p0.w, half)));
    float s1 = merge_lse(la1, plse4(gsel_hi(x, p1.x, half), gsel_hi(x, p1.y, half),
                                    gsel_hi(x, p1.z, half), gsel_hi(x, p1.w, half)));
    float s2 = merge_lse(la2, plse4(gsel_hi(x, p2.x, half), gsel_hi(x, p2.y, half),
                                    gsel_hi(x, p2.z, half), gsel_hi(x, p2.w, half)));
    float s3 = merge_lse(la3, plse4(gsel_hi(x, p3.x, half), gsel_hi(x, p3.y, half),
                                    gsel_hi(x, p3.z, half), gsel_hi(x, p3.w, half)));

    if (act) {
        if (base + 3 < n) {
            v4h o; o.x = (_Float16)s0; o.y = (_Float16)s1; o.z = (_Float16)s2; o.w = (_Float16)s3;
            __builtin_nontemporal_store(o, reinterpret_cast<v4h*>(y + base));
        } else {
            y[base] = (_Float16)s0;
            if (base + 1 < n) y[base + 1] = (_Float16)s1;
            if (base + 2 < n) y[base + 2] = (_Float16)s2;
        }
    }
}

// Product node (layer 2): 4 consecutive nodes/thread, one 8B store.
__global__ __launch_bounds__(256) void sum4_h2h_kernel(const _Float16* __restrict__ x,
                                                       const v4i* __restrict__ ptrs,
                                                       _Float16* __restrict__ y, int n, int h) {
    int t = blockIdx.x * blockDim.x + threadIdx.x;
    if (t >= h) return;
    int base = t << 2;
    int b1 = base + 1 < n ? base + 1 : 0;
    int b2 = base + 2 < n ? base + 2 : 0;
    int b3 = base + 3 < n ? base + 3 : 0;
    v4i p0 = __builtin_nontemporal_load(ptrs + base);
    v4i p1 = __builtin_nontemporal_load(ptrs + b1);
    v4i p2 = __builtin_nontemporal_load(ptrs + b2);
    v4i p3 = __builtin_nontemporal_load(ptrs + b3);
    float s0 = ((float)x[p0.x] + (float)x[p0.y]) + ((float)x[p0.z] + (float)x[p0.w]);
    float s1 = ((float)x[p1.x] + (float)x[p1.y]) + ((float)x[p1.z] + (float)x[p1.w]);
    float s2 = ((float)x[p2.x] + (float)x[p2.y]) + ((float)x[p2.z] + (float)x[p2.w]);
    float s3 = ((float)x[p3.x] + (float)x[p3.y]) + ((float)x[p3.z] + (float)x[p3.w]);
    if (base + 3 < n) {
        v4h o; o.x = (_Float16)s0; o.y = (_Float16)s1; o.z = (_Float16)s2; o.w = (_Float16)s3;
        __builtin_nontemporal_store(o, reinterpret_cast<v4h*>(y + base));
    } else {
        y[base] = (_Float16)s0;
        if (base + 1 < n) y[base + 1] = (_Float16)s1;
        if (base + 2 < n) y[base + 2] = (_Float16)s2;
    }
}

__device__ __forceinline__ float lse4(float a, float b, float c, float d) {
    float m = fmaxf(fmaxf(a, b), fmaxf(c, d));
    if (m == NEG_INF) return NEG_INF;
    float s = __expf(a - m) + __expf(b - m) + __expf(c - m) + __expf(d - m) + 1e-15f;
    return __logf(s) + m;
}

// Final sum node (layer 3): 2 consecutive nodes/thread, one 8B fp32 store.
__global__ __launch_bounds__(256) void logsum4_h2f_kernel(const _Float16* __restrict__ x,
                                                          const v4i* __restrict__ ptrs,
                                                          float* __restrict__ y, int n, int h) {
    int t = blockIdx.x * blockDim.x + threadIdx.x;
    if (t >= h) return;
    int base = t << 1;
    int b1 = base + 1 < n ? base + 1 : 0;
    v4i p0 = __builtin_nontemporal_load(ptrs + base);
    v4i p1 = __builtin_nontemporal_load(ptrs + b1);
    float r0 = lse4((float)x[p0.x], (float)x[p0.y], (float)x[p0.z], (float)x[p0.w]);
    float r1 = lse4((float)x[p1.x], (float)x[p1.y], (float)x[p1.z], (float)x[p1.w]);
    if (base + 1 < n) {
        v2f o; o.x = r0; o.y = r1;
        __builtin_nontemporal_store(o, reinterpret_cast<v2f*>(y + base));
    } else {
        y[base] = r0;
    }
}

extern "C" void kernel_launch(void* const* d_in, const int* in_sizes, int n_in,
                              void* d_out, int out_size, void* d_ws, size_t ws_size,
                              hipStream_t stream) {
    // d_in dict order: weights, ptrs0, csr0, n0, ptrs1, csr1, n1, ptrs2, csr2, n2, ptrs3, csr3, n3
    const float* w     = (const float*)d_in[0];
    const v4i*   ptrs0 = (const v4i*)d_in[1];
    const v4i*   ptrs1 = (const v4i*)d_in[4];
    const v4i*   ptrs2 = (const v4i*)d_in[7];
    const v4i*   ptrs3 = (const v4i*)d_in[10];

    const int n_vars = in_sizes[0];
    const int n0 = in_sizes[1] / 4;
    const int n1 = in_sizes[4] / 4;
    const int n2 = in_sizes[7] / 4;
    const int n3 = in_sizes[10] / 4;

    // workspace layout (256B-aligned), intermediates fp16
    char* ws = (char*)d_ws;
    size_t off = 0;
    _Float16* wh = (_Float16*)(ws + off); off += ((size_t)n_vars * 2 + 255) & ~(size_t)255;
    _Float16* y0 = (_Float16*)(ws + off); off += ((size_t)n0 * 2 + 255) & ~(size_t)255;
    _Float16* y1 = (_Float16*)(ws + off); off += ((size_t)n1 * 2 + 255) & ~(size_t)255;
    _Float16* y2 = (_Float16*)(ws + off);
    float* out = (float*)d_out;

    const int B = 256;
    int hc = (n_vars + 3) / 4;
    int h0 = (n0 + 3) / 4;                 // enc: 4 nodes/thread
    int h1 = (n1 + 3) / 4;                 // l1 fused: 4 nodes/thread (500K threads)
    int h2 = (n2 + 3) / 4;                 // l2: 4 nodes/thread
    int h3 = (n3 + 1) / 2;                 // l3: 2 nodes/thread
    int half0 = n0 / 2;                    // 4 MB fp16 boundary of y0

    cvt_kernel        <<<(hc + B - 1) / B, B, 0, stream>>>(w, wh, n_vars);
    sum4_enc_kernel   <<<(h0 + B - 1) / B, B, 0, stream>>>(wh, ptrs0, y0, n0, h0);
    l1_fused_kernel   <<<(h1 + B - 1) / B, B, 0, stream>>>(y0, ptrs1, y1, n1, h1, half0);
    sum4_h2h_kernel   <<<(h2 + B - 1) / B, B, 0, stream>>>(y1, ptrs2, y2, n2, h2);
    logsum4_h2f_kernel<<<(h3 + B - 1) / B, B, 0, stream>>>(y2, ptrs3, out, n3, h3);
}

// Round 6
// 367.889 us; speedup vs baseline: 3.4020x; 1.0538x over previous
//
#include <hip/hip_runtime.h>
#include <math.h>

#define NEG_INF (-INFINITY)

typedef int      v4i __attribute__((ext_vector_type(4)));
typedef float    v4f __attribute__((ext_vector_type(4)));
typedef _Float16 v4h __attribute__((ext_vector_type(4)));

// fast log1mexp for v < 0: log(1 - e^v). Rel err ~1e-6.
__device__ __forceinline__ float fast_log1mexp(float v) {
    if (v > -0.125f) {
        float e = v * (1.0f + v * (0.5f + v * (0.16666667f + v * 0.041666667f)));
        return __logf(-e);
    }
    return __logf(1.0f - __expf(v));
}

// w (fp32) -> wh (fp16)
__global__ __launch_bounds__(256) void cvt_kernel(const float* __restrict__ w,
                                                  _Float16* __restrict__ wh, int n) {
    int i = blockIdx.x * blockDim.x + threadIdx.x;
    int n4 = n >> 2;
    if (i < n4) {
        v4f v = reinterpret_cast<const v4f*>(w)[i];
        v4h o;
        o.x = (_Float16)v.x; o.y = (_Float16)v.y;
        o.z = (_Float16)v.z; o.w = (_Float16)v.w;
        reinterpret_cast<v4h*>(wh)[i] = o;
    }
    int base = n4 << 2;
    if (i < (n - base)) wh[base + i] = (_Float16)w[base + i];
}

// encoded-x ptr -> clamped index into wh
__device__ __forceinline__ int widx(int p) { int j = (p >> 1) - 1; return j < 0 ? 0 : j; }
// fixup a raw gathered weight per ptr parity/constants
__device__ __forceinline__ float fixw(int p, float v) {
    float r = (p & 1) ? fast_log1mexp(v) : v;
    if (p < 2) r = (p == 0) ? NEG_INF : 0.0f;
    return r;
}

// Layer 0: product node fused with encode. STRIDED 4 nodes/thread (coalesced
// ptr streams — round-5 showed consecutive blocking decoalesces ptr loads,
// +30MB FETCH, +10us). Split into two half-range dispatches [off, off+range)
// so enc vacates the top-5 profile table and l1's counters become visible.
__global__ __launch_bounds__(256) void sum4_enc_kernel(const _Float16* __restrict__ wh,
                                                       const v4i* __restrict__ ptrs,
                                                       _Float16* __restrict__ y,
                                                       int off, int n, int h) {
    int t = blockIdx.x * blockDim.x + threadIdx.x;
    if (t >= h) return;
    int i0 = off + t, i1 = i0 + h, i2 = i0 + 2 * h, i3 = i0 + 3 * h;
    int c1 = i1 < n ? i1 : 0, c2 = i2 < n ? i2 : 0, c3 = i3 < n ? i3 : 0;
    v4i p0 = __builtin_nontemporal_load(ptrs + i0);
    v4i p1 = __builtin_nontemporal_load(ptrs + c1);
    v4i p2 = __builtin_nontemporal_load(ptrs + c2);
    v4i p3 = __builtin_nontemporal_load(ptrs + c3);
    float g00 = (float)wh[widx(p0.x)], g01 = (float)wh[widx(p0.y)];
    float g02 = (float)wh[widx(p0.z)], g03 = (float)wh[widx(p0.w)];
    float g10 = (float)wh[widx(p1.x)], g11 = (float)wh[widx(p1.y)];
    float g12 = (float)wh[widx(p1.z)], g13 = (float)wh[widx(p1.w)];
    float g20 = (float)wh[widx(p2.x)], g21 = (float)wh[widx(p2.y)];
    float g22 = (float)wh[widx(p2.z)], g23 = (float)wh[widx(p2.w)];
    float g30 = (float)wh[widx(p3.x)], g31 = (float)wh[widx(p3.y)];
    float g32 = (float)wh[widx(p3.z)], g33 = (float)wh[widx(p3.w)];
    float s0 = (fixw(p0.x, g00) + fixw(p0.y, g01)) + (fixw(p0.z, g02) + fixw(p0.w, g03));
    float s1 = (fixw(p1.x, g10) + fixw(p1.y, g11)) + (fixw(p1.z, g12) + fixw(p1.w, g13));
    float s2 = (fixw(p2.x, g20) + fixw(p2.y, g21)) + (fixw(p2.z, g22) + fixw(p2.w, g23));
    float s3 = (fixw(p3.x, g30) + fixw(p3.y, g31)) + (fixw(p3.z, g32) + fixw(p3.w, g33));
    __builtin_nontemporal_store((_Float16)s0, y + i0);
    if (i1 < n) __builtin_nontemporal_store((_Float16)s1, y + i1);
    if (i2 < n) __builtin_nontemporal_store((_Float16)s2, y + i2);
    if (i3 < n) __builtin_nontemporal_store((_Float16)s3, y + i3);
}

// partial stable LSE (no epsilon): -inf if all inputs -inf.
__device__ __forceinline__ float plse4(float a, float b, float c, float d) {
    float m = fmaxf(fmaxf(a, b), fmaxf(c, d));
    if (m == NEG_INF) return NEG_INF;
    float s = __expf(a - m) + __expf(b - m) + __expf(c - m) + __expf(d - m);
    return __logf(s) + m;
}

// exact two-way LSE merge (epsilon once, matching ref)
__device__ __forceinline__ float merge_lse(float LA, float LB) {
    float m = fmaxf(LA, LB);
    if (m == NEG_INF) return NEG_INF;
    float s = __expf(LA - m) + __expf(LB - m) + 1e-15f;
    return __logf(s) + m;
}

// address-clamp gather: NO exec-mask predication. hipcc can't speculate the
// load under a ternary (can't prove dereferenceability), so `cond ? x[p] : -inf`
// becomes saveexec-guarded loads. Clamping the ADDRESS forces an unconditional
// load (wrong-phase lanes coalesce onto one cached line) + value cndmask.
__device__ __forceinline__ float gsel_lo(const _Float16* __restrict__ x, int p, int half) {
    int q = p < half ? p : 0;
    float v = (float)x[q];
    return p < half ? v : NEG_INF;
}
__device__ __forceinline__ float gsel_hi(const _Float16* __restrict__ x, int p, int half) {
    int q = p >= half ? p : half;
    float v = (float)x[q];
    return p >= half ? v : NEG_INF;
}

// Layer 1 (sum node): fused two-phase kernel, STRIDED 4 nodes/thread, partial
// LSE carried in registers across the block-level phase aligner.
// Phase A working set = lower 4MB of y0 (per-XCD-L2-sized), phase B = upper.
__global__ __launch_bounds__(256) void l1_fused_kernel(const _Float16* __restrict__ x,
                                                       const v4i* __restrict__ ptrs,
                                                       _Float16* __restrict__ y,
                                                       int n, int h, int half) {
    int t = blockIdx.x * blockDim.x + threadIdx.x;
    bool act = t < h;
    int tt = act ? t : 0;
    int i0 = tt, i1 = tt + h, i2 = tt + 2 * h, i3 = tt + 3 * h;
    int c1 = i1 < n ? i1 : 0, c2 = i2 < n ? i2 : 0, c3 = i3 < n ? i3 : 0;
    v4i p0 = __builtin_nontemporal_load(ptrs + i0);
    v4i p1 = __builtin_nontemporal_load(ptrs + c1);
    v4i p2 = __builtin_nontemporal_load(ptrs + c2);
    v4i p3 = __builtin_nontemporal_load(ptrs + c3);

    // phase A: lower-half working set (address-clamped, unconditional loads)
    float la0 = plse4(gsel_lo(x, p0.x, half), gsel_lo(x, p0.y, half),
                      gsel_lo(x, p0.z, half), gsel_lo(x, p0.w, half));
    float la1 = plse4(gsel_lo(x, p1.x, half), gsel_lo(x, p1.y, half),
                      gsel_lo(x, p1.z, half), gsel_lo(x, p1.w, half));
    float la2 = plse4(gsel_lo(x, p2.x, half), gsel_lo(x, p2.y, half),
                      gsel_lo(x, p2.z, half), gsel_lo(x, p2.w, half));
    float la3 = plse4(gsel_lo(x, p3.x, half), gsel_lo(x, p3.y, half),
                      gsel_lo(x, p3.z, half), gsel_lo(x, p3.w, half));

    __syncthreads();  // phase aligner: co-resident waves keep working sets separated

    // phase B: upper-half working set + merge
    float s0 = merge_lse(la0, plse4(gsel_hi(x, p0.x, half), gsel_hi(x, p0.y, half),
                                    gsel_hi(x, p0.z, half), gsel_hi(x, p0.w, half)));
    float s1 = merge_lse(la1, plse4(gsel_hi(x, p1.x, half), gsel_hi(x, p1.y, half),
                                    gsel_hi(x, p1.z, half), gsel_hi(x, p1.w, half)));
    float s2 = merge_lse(la2, plse4(gsel_hi(x, p2.x, half), gsel_hi(x, p2.y, half),
                                    gsel_hi(x, p2.z, half), gsel_hi(x, p2.w, half)));
    float s3 = merge_lse(la3, plse4(gsel_hi(x, p3.x, half), gsel_hi(x, p3.y, half),
                                    gsel_hi(x, p3.z, half), gsel_hi(x, p3.w, half)));

    if (act) {
        __builtin_nontemporal_store((_Float16)s0, y + i0);
        if (i1 < n) __builtin_nontemporal_store((_Float16)s1, y + i1);
        if (i2 < n) __builtin_nontemporal_store((_Float16)s2, y + i2);
        if (i3 < n) __builtin_nontemporal_store((_Float16)s3, y + i3);
    }
}

// Product node (layer 2): STRIDED 2 nodes/thread -> 500K threads.
__global__ __launch_bounds__(256) void sum4_h2h_kernel(const _Float16* __restrict__ x,
                                                       const v4i* __restrict__ ptrs,
                                                       _Float16* __restrict__ y, int n, int h) {
    int t = blockIdx.x * blockDim.x + threadIdx.x;
    if (t >= h) return;
    int i0 = t, i1 = t + h;
    int c1 = i1 < n ? i1 : 0;
    v4i p0 = __builtin_nontemporal_load(ptrs + i0);
    v4i p1 = __builtin_nontemporal_load(ptrs + c1);
    float s0 = ((float)x[p0.x] + (float)x[p0.y]) + ((float)x[p0.z] + (float)x[p0.w]);
    float s1 = ((float)x[p1.x] + (float)x[p1.y]) + ((float)x[p1.z] + (float)x[p1.w]);
    __builtin_nontemporal_store((_Float16)s0, y + i0);
    if (i1 < n) __builtin_nontemporal_store((_Float16)s1, y + i1);
}

__device__ __forceinline__ float lse4(float a, float b, float c, float d) {
    float m = fmaxf(fmaxf(a, b), fmaxf(c, d));
    if (m == NEG_INF) return NEG_INF;
    float s = __expf(a - m) + __expf(b - m) + __expf(c - m) + __expf(d - m) + 1e-15f;
    return __logf(s) + m;
}

// Final sum node (layer 3): 1 node/thread -> 500K threads.
__global__ __launch_bounds__(256) void logsum4_h2f_kernel(const _Float16* __restrict__ x,
                                                          const v4i* __restrict__ ptrs,
                                                          float* __restrict__ y, int n) {
    int t = blockIdx.x * blockDim.x + threadIdx.x;
    if (t >= n) return;
    v4i p = __builtin_nontemporal_load(ptrs + t);
    float r = lse4((float)x[p.x], (float)x[p.y], (float)x[p.z], (float)x[p.w]);
    __builtin_nontemporal_store(r, y + t);
}

extern "C" void kernel_launch(void* const* d_in, const int* in_sizes, int n_in,
                              void* d_out, int out_size, void* d_ws, size_t ws_size,
                              hipStream_t stream) {
    // d_in dict order: weights, ptrs0, csr0, n0, ptrs1, csr1, n1, ptrs2, csr2, n2, ptrs3, csr3, n3
    const float* w     = (const float*)d_in[0];
    const v4i*   ptrs0 = (const v4i*)d_in[1];
    const v4i*   ptrs1 = (const v4i*)d_in[4];
    const v4i*   ptrs2 = (const v4i*)d_in[7];
    const v4i*   ptrs3 = (const v4i*)d_in[10];

    const int n_vars = in_sizes[0];
    const int n0 = in_sizes[1] / 4;
    const int n1 = in_sizes[4] / 4;
    const int n2 = in_sizes[7] / 4;
    const int n3 = in_sizes[10] / 4;

    // workspace layout (256B-aligned), intermediates fp16
    char* ws = (char*)d_ws;
    size_t off = 0;
    _Float16* wh = (_Float16*)(ws + off); off += ((size_t)n_vars * 2 + 255) & ~(size_t)255;
    _Float16* y0 = (_Float16*)(ws + off); off += ((size_t)n0 * 2 + 255) & ~(size_t)255;
    _Float16* y1 = (_Float16*)(ws + off); off += ((size_t)n1 * 2 + 255) & ~(size_t)255;
    _Float16* y2 = (_Float16*)(ws + off);
    float* out = (float*)d_out;

    const int B = 256;
    int hc = (n_vars + 3) / 4;
    int mid0 = n0 / 2;                      // enc split point (2M)
    int hA = (mid0 + 3) / 4;                // enc half A: 4 nodes/thread over [0, mid0)
    int hB = (n0 - mid0 + 3) / 4;           // enc half B: over [mid0, n0)
    int h1 = (n1 + 3) / 4;                  // l1 fused: 4 nodes/thread
    int h2 = (n2 + 1) / 2;                  // l2: 2 nodes/thread
    int half0 = n0 / 2;                     // 4 MB fp16 boundary of y0

    cvt_kernel        <<<(hc + B - 1) / B, B, 0, stream>>>(w, wh, n_vars);
    sum4_enc_kernel   <<<(hA + B - 1) / B, B, 0, stream>>>(wh, ptrs0, y0, 0, mid0, hA);
    sum4_enc_kernel   <<<(hB + B - 1) / B, B, 0, stream>>>(wh, ptrs0, y0, mid0, n0, hB);
    l1_fused_kernel   <<<(h1 + B - 1) / B, B, 0, stream>>>(y0, ptrs1, y1, n1, h1, half0);
    sum4_h2h_kernel   <<<(h2 + B - 1) / B, B, 0, stream>>>(y1, ptrs2, y2, n2, h2);
    logsum4_h2f_kernel<<<(n3 + B - 1) / B, B, 0, stream>>>(y2, ptrs3, out, n3);
}

// Round 7
// 366.063 us; speedup vs baseline: 3.4189x; 1.0050x over previous
//
#include <hip/hip_runtime.h>
#include <math.h>

#define NEG_INF (-INFINITY)

typedef int      v4i __attribute__((ext_vector_type(4)));
typedef float    v4f __attribute__((ext_vector_type(4)));
typedef _Float16 v4h __attribute__((ext_vector_type(4)));

// fast log1mexp for v < 0: log(1 - e^v). Rel err ~1e-6.
__device__ __forceinline__ float fast_log1mexp(float v) {
    if (v > -0.125f) {
        float e = v * (1.0f + v * (0.5f + v * (0.16666667f + v * 0.041666667f)));
        return __logf(-e);
    }
    return __logf(1.0f - __expf(v));
}

// w (fp32) -> wh (fp16). Plain stores: wh is consumed by enc's gathers, must
// land in L2/LLC (this is why enc's FETCH was already near-ideal).
__global__ __launch_bounds__(256) void cvt_kernel(const float* __restrict__ w,
                                                  _Float16* __restrict__ wh, int n) {
    int i = blockIdx.x * blockDim.x + threadIdx.x;
    int n4 = n >> 2;
    if (i < n4) {
        v4f v = reinterpret_cast<const v4f*>(w)[i];
        v4h o;
        o.x = (_Float16)v.x; o.y = (_Float16)v.y;
        o.z = (_Float16)v.z; o.w = (_Float16)v.w;
        reinterpret_cast<v4h*>(wh)[i] = o;
    }
    int base = n4 << 2;
    if (i < (n - base)) wh[base + i] = (_Float16)w[base + i];
}

// encoded-x ptr -> clamped index into wh
__device__ __forceinline__ int widx(int p) { int j = (p >> 1) - 1; return j < 0 ? 0 : j; }
// fixup a raw gathered weight per ptr parity/constants
__device__ __forceinline__ float fixw(int p, float v) {
    float r = (p & 1) ? fast_log1mexp(v) : v;
    if (p < 2) r = (p == 0) ? NEG_INF : 0.0f;
    return r;
}

// Layer 0: product node fused with encode. STRIDED 4 nodes/thread (coalesced
// ptr streams — round-5: consecutive blocking decoalesces, +30MB FETCH).
// PLAIN stores to y0: round-6 showed nontemporal stores on intermediates
// bypass L2/LLC, making the consumer (l1) re-fetch 223MB from HBM.
__global__ __launch_bounds__(256) void sum4_enc_kernel(const _Float16* __restrict__ wh,
                                                       const v4i* __restrict__ ptrs,
                                                       _Float16* __restrict__ y, int n, int h) {
    int t = blockIdx.x * blockDim.x + threadIdx.x;
    if (t >= h) return;
    int i0 = t, i1 = t + h, i2 = t + 2 * h, i3 = t + 3 * h;
    int c1 = i1 < n ? i1 : 0, c2 = i2 < n ? i2 : 0, c3 = i3 < n ? i3 : 0;
    v4i p0 = __builtin_nontemporal_load(ptrs + i0);
    v4i p1 = __builtin_nontemporal_load(ptrs + c1);
    v4i p2 = __builtin_nontemporal_load(ptrs + c2);
    v4i p3 = __builtin_nontemporal_load(ptrs + c3);
    float g00 = (float)wh[widx(p0.x)], g01 = (float)wh[widx(p0.y)];
    float g02 = (float)wh[widx(p0.z)], g03 = (float)wh[widx(p0.w)];
    float g10 = (float)wh[widx(p1.x)], g11 = (float)wh[widx(p1.y)];
    float g12 = (float)wh[widx(p1.z)], g13 = (float)wh[widx(p1.w)];
    float g20 = (float)wh[widx(p2.x)], g21 = (float)wh[widx(p2.y)];
    float g22 = (float)wh[widx(p2.z)], g23 = (float)wh[widx(p2.w)];
    float g30 = (float)wh[widx(p3.x)], g31 = (float)wh[widx(p3.y)];
    float g32 = (float)wh[widx(p3.z)], g33 = (float)wh[widx(p3.w)];
    float s0 = (fixw(p0.x, g00) + fixw(p0.y, g01)) + (fixw(p0.z, g02) + fixw(p0.w, g03));
    float s1 = (fixw(p1.x, g10) + fixw(p1.y, g11)) + (fixw(p1.z, g12) + fixw(p1.w, g13));
    float s2 = (fixw(p2.x, g20) + fixw(p2.y, g21)) + (fixw(p2.z, g22) + fixw(p2.w, g23));
    float s3 = (fixw(p3.x, g30) + fixw(p3.y, g31)) + (fixw(p3.z, g32) + fixw(p3.w, g33));
    y[i0] = (_Float16)s0;
    if (i1 < n) y[i1] = (_Float16)s1;
    if (i2 < n) y[i2] = (_Float16)s2;
    if (i3 < n) y[i3] = (_Float16)s3;
}

// partial stable LSE (no epsilon): -inf if all inputs -inf.
__device__ __forceinline__ float plse4(float a, float b, float c, float d) {
    float m = fmaxf(fmaxf(a, b), fmaxf(c, d));
    if (m == NEG_INF) return NEG_INF;
    float s = __expf(a - m) + __expf(b - m) + __expf(c - m) + __expf(d - m);
    return __logf(s) + m;
}

// exact two-way LSE merge (epsilon once, matching ref)
__device__ __forceinline__ float merge_lse(float LA, float LB) {
    float m = fmaxf(LA, LB);
    if (m == NEG_INF) return NEG_INF;
    float s = __expf(LA - m) + __expf(LB - m) + 1e-15f;
    return __logf(s) + m;
}

// address-clamp gather: unconditional load (wrong-phase lanes coalesce onto
// one cached line) + value cndmask. Avoids saveexec-guarded load chains.
__device__ __forceinline__ float gsel_lo(const _Float16* __restrict__ x, int p, int half) {
    int q = p < half ? p : 0;
    float v = (float)x[q];
    return p < half ? v : NEG_INF;
}
__device__ __forceinline__ float gsel_hi(const _Float16* __restrict__ x, int p, int half) {
    int q = p >= half ? p : half;
    float v = (float)x[q];
    return p >= half ? v : NEG_INF;
}

// Layer 1 (sum node): fused two-phase kernel, STRIDED 4 nodes/thread, partial
// LSE carried in registers across the block-level phase aligner.
// Phase A working set = lower 4MB of y0 (per-XCD-L2-sized), phase B = upper.
// Plain stores to y1 (consumed by l2's gathers).
__global__ __launch_bounds__(256) void l1_fused_kernel(const _Float16* __restrict__ x,
                                                       const v4i* __restrict__ ptrs,
                                                       _Float16* __restrict__ y,
                                                       int n, int h, int half) {
    int t = blockIdx.x * blockDim.x + threadIdx.x;
    bool act = t < h;
    int tt = act ? t : 0;
    int i0 = tt, i1 = tt + h, i2 = tt + 2 * h, i3 = tt + 3 * h;
    int c1 = i1 < n ? i1 : 0, c2 = i2 < n ? i2 : 0, c3 = i3 < n ? i3 : 0;
    v4i p0 = __builtin_nontemporal_load(ptrs + i0);
    v4i p1 = __builtin_nontemporal_load(ptrs + c1);
    v4i p2 = __builtin_nontemporal_load(ptrs + c2);
    v4i p3 = __builtin_nontemporal_load(ptrs + c3);

    // phase A: lower-half working set (address-clamped, unconditional loads)
    float la0 = plse4(gsel_lo(x, p0.x, half), gsel_lo(x, p0.y, half),
                      gsel_lo(x, p0.z, half), gsel_lo(x, p0.w, half));
    float la1 = plse4(gsel_lo(x, p1.x, half), gsel_lo(x, p1.y, half),
                      gsel_lo(x, p1.z, half), gsel_lo(x, p1.w, half));
    float la2 = plse4(gsel_lo(x, p2.x, half), gsel_lo(x, p2.y, half),
                      gsel_lo(x, p2.z, half), gsel_lo(x, p2.w, half));
    float la3 = plse4(gsel_lo(x, p3.x, half), gsel_lo(x, p3.y, half),
                      gsel_lo(x, p3.z, half), gsel_lo(x, p3.w, half));

    __syncthreads();  // phase aligner: co-resident waves keep working sets separated

    // phase B: upper-half working set + merge
    float s0 = merge_lse(la0, plse4(gsel_hi(x, p0.x, half), gsel_hi(x, p0.y, half),
                                    gsel_hi(x, p0.z, half), gsel_hi(x, p0.w, half)));
    float s1 = merge_lse(la1, plse4(gsel_hi(x, p1.x, half), gsel_hi(x, p1.y, half),
                                    gsel_hi(x, p1.z, half), gsel_hi(x, p1.w, half)));
    float s2 = merge_lse(la2, plse4(gsel_hi(x, p2.x, half), gsel_hi(x, p2.y, half),
                                    gsel_hi(x, p2.z, half), gsel_hi(x, p2.w, half)));
    float s3 = merge_lse(la3, plse4(gsel_hi(x, p3.x, half), gsel_hi(x, p3.y, half),
                                    gsel_hi(x, p3.z, half), gsel_hi(x, p3.w, half)));

    if (act) {
        y[i0] = (_Float16)s0;
        if (i1 < n) y[i1] = (_Float16)s1;
        if (i2 < n) y[i2] = (_Float16)s2;
        if (i3 < n) y[i3] = (_Float16)s3;
    }
}

// Product node (layer 2): STRIDED 2 nodes/thread. Plain stores to y2.
__global__ __launch_bounds__(256) void sum4_h2h_kernel(const _Float16* __restrict__ x,
                                                       const v4i* __restrict__ ptrs,
                                                       _Float16* __restrict__ y, int n, int h) {
    int t = blockIdx.x * blockDim.x + threadIdx.x;
    if (t >= h) return;
    int i0 = t, i1 = t + h;
    int c1 = i1 < n ? i1 : 0;
    v4i p0 = __builtin_nontemporal_load(ptrs + i0);
    v4i p1 = __builtin_nontemporal_load(ptrs + c1);
    float s0 = ((float)x[p0.x] + (float)x[p0.y]) + ((float)x[p0.z] + (float)x[p0.w]);
    float s1 = ((float)x[p1.x] + (float)x[p1.y]) + ((float)x[p1.z] + (float)x[p1.w]);
    y[i0] = (_Float16)s0;
    if (i1 < n) y[i1] = (_Float16)s1;
}

__device__ __forceinline__ float lse4(float a, float b, float c, float d) {
    float m = fmaxf(fmaxf(a, b), fmaxf(c, d));
    if (m == NEG_INF) return NEG_INF;
    float s = __expf(a - m) + __expf(b - m) + __expf(c - m) + __expf(d - m) + 1e-15f;
    return __logf(s) + m;
}

// Final sum node (layer 3): 1 node/thread. out has no GPU consumer -> nt store OK.
__global__ __launch_bounds__(256) void logsum4_h2f_kernel(const _Float16* __restrict__ x,
                                                          const v4i* __restrict__ ptrs,
                                                          float* __restrict__ y, int n) {
    int t = blockIdx.x * blockDim.x + threadIdx.x;
    if (t >= n) return;
    v4i p = __builtin_nontemporal_load(ptrs + t);
    float r = lse4((float)x[p.x], (float)x[p.y], (float)x[p.z], (float)x[p.w]);
    __builtin_nontemporal_store(r, y + t);
}

extern "C" void kernel_launch(void* const* d_in, const int* in_sizes, int n_in,
                              void* d_out, int out_size, void* d_ws, size_t ws_size,
                              hipStream_t stream) {
    // d_in dict order: weights, ptrs0, csr0, n0, ptrs1, csr1, n1, ptrs2, csr2, n2, ptrs3, csr3, n3
    const float* w     = (const float*)d_in[0];
    const v4i*   ptrs0 = (const v4i*)d_in[1];
    const v4i*   ptrs1 = (const v4i*)d_in[4];
    const v4i*   ptrs2 = (const v4i*)d_in[7];
    const v4i*   ptrs3 = (const v4i*)d_in[10];

    const int n_vars = in_sizes[0];
    const int n0 = in_sizes[1] / 4;
    const int n1 = in_sizes[4] / 4;
    const int n2 = in_sizes[7] / 4;
    const int n3 = in_sizes[10] / 4;

    // workspace layout (256B-aligned), intermediates fp16
    char* ws = (char*)d_ws;
    size_t off = 0;
    _Float16* wh = (_Float16*)(ws + off); off += ((size_t)n_vars * 2 + 255) & ~(size_t)255;
    _Float16* y0 = (_Float16*)(ws + off); off += ((size_t)n0 * 2 + 255) & ~(size_t)255;
    _Float16* y1 = (_Float16*)(ws + off); off += ((size_t)n1 * 2 + 255) & ~(size_t)255;
    _Float16* y2 = (_Float16*)(ws + off);
    float* out = (float*)d_out;

    const int B = 256;
    int hc = (n_vars + 3) / 4;
    int h0 = (n0 + 3) / 4;                 // enc: 4 nodes/thread (single dispatch again)
    int h1 = (n1 + 3) / 4;                 // l1 fused: 4 nodes/thread
    int h2 = (n2 + 1) / 2;                 // l2: 2 nodes/thread
    int half0 = n0 / 2;                    // 4 MB fp16 boundary of y0

    cvt_kernel        <<<(hc + B - 1) / B, B, 0, stream>>>(w, wh, n_vars);
    sum4_enc_kernel   <<<(h0 + B - 1) / B, B, 0, stream>>>(wh, ptrs0, y0, n0, h0);
    l1_fused_kernel   <<<(h1 + B - 1) / B, B, 0, stream>>>(y0, ptrs1, y1, n1, h1, half0);
    sum4_h2h_kernel   <<<(h2 + B - 1) / B, B, 0, stream>>>(y1, ptrs2, y2, n2, h2);
    logsum4_h2f_kernel<<<(n3 + B - 1) / B, B, 0, stream>>>(y2, ptrs3, out, n3);
}

// Round 8
// 354.019 us; speedup vs baseline: 3.5352x; 1.0340x over previous
//
#include <hip/hip_runtime.h>
#include <math.h>

#define NEG_INF (-INFINITY)

typedef int      v4i __attribute__((ext_vector_type(4)));
typedef float    v4f __attribute__((ext_vector_type(4)));
typedef _Float16 v4h __attribute__((ext_vector_type(4)));

// fast log1mexp for v < 0: log(1 - e^v). Rel err ~1e-6.
__device__ __forceinline__ float fast_log1mexp(float v) {
    if (v > -0.125f) {
        float e = v * (1.0f + v * (0.5f + v * (0.16666667f + v * 0.041666667f)));
        return __logf(-e);
    }
    return __logf(1.0f - __expf(v));
}

// w (fp32) -> wh (fp16). Plain stores (consumer gathers must find it in L2/LLC).
__global__ __launch_bounds__(256) void cvt_kernel(const float* __restrict__ w,
                                                  _Float16* __restrict__ wh, int n) {
    int i = blockIdx.x * blockDim.x + threadIdx.x;
    int n4 = n >> 2;
    if (i < n4) {
        v4f v = reinterpret_cast<const v4f*>(w)[i];
        v4h o;
        o.x = (_Float16)v.x; o.y = (_Float16)v.y;
        o.z = (_Float16)v.z; o.w = (_Float16)v.w;
        reinterpret_cast<v4h*>(wh)[i] = o;
    }
    int base = n4 << 2;
    if (i < (n - base)) wh[base + i] = (_Float16)w[base + i];
}

// encoded-x ptr -> clamped index into wh
__device__ __forceinline__ int widx(int p) { int j = (p >> 1) - 1; return j < 0 ? 0 : j; }
// fixup a raw gathered weight per ptr parity/constants
__device__ __forceinline__ float fixw(int p, float v) {
    float r = (p & 1) ? fast_log1mexp(v) : v;
    if (p < 2) r = (p == 0) ? NEG_INF : 0.0f;
    return r;
}

// PROBE (round 8): L1-bypassing gather. Random gathers into a 4MB table have
// <1% L1 hit rate, so L1 allocation only burns MSHRs. Agent-scope relaxed
// atomic load emits `sc0` (L1 read-through) — outstanding-line budget moves
// from L1 MSHRs (~64, measured 0.31 lines/cy/CU = 64/200cy) to the L2 queue.
__device__ __forceinline__ float gw_sc0(const unsigned short* __restrict__ xs, int q) {
    unsigned short u = __hip_atomic_load(xs + q, __ATOMIC_RELAXED, __HIP_MEMORY_SCOPE_AGENT);
    _Float16 hv;
    __builtin_memcpy(&hv, &u, 2);
    return (float)hv;
}

// Layer 0: product node fused with encode. STRIDED 4 nodes/thread (coalesced
// ptr streams). wh gathers via sc0 (L1-bypass probe). Plain y0 stores.
__global__ __launch_bounds__(256) void sum4_enc_kernel(const _Float16* __restrict__ wh,
                                                       const v4i* __restrict__ ptrs,
                                                       _Float16* __restrict__ y, int n, int h) {
    const unsigned short* whu = reinterpret_cast<const unsigned short*>(wh);
    int t = blockIdx.x * blockDim.x + threadIdx.x;
    if (t >= h) return;
    int i0 = t, i1 = t + h, i2 = t + 2 * h, i3 = t + 3 * h;
    int c1 = i1 < n ? i1 : 0, c2 = i2 < n ? i2 : 0, c3 = i3 < n ? i3 : 0;
    v4i p0 = __builtin_nontemporal_load(ptrs + i0);
    v4i p1 = __builtin_nontemporal_load(ptrs + c1);
    v4i p2 = __builtin_nontemporal_load(ptrs + c2);
    v4i p3 = __builtin_nontemporal_load(ptrs + c3);
    float g00 = gw_sc0(whu, widx(p0.x)), g01 = gw_sc0(whu, widx(p0.y));
    float g02 = gw_sc0(whu, widx(p0.z)), g03 = gw_sc0(whu, widx(p0.w));
    float g10 = gw_sc0(whu, widx(p1.x)), g11 = gw_sc0(whu, widx(p1.y));
    float g12 = gw_sc0(whu, widx(p1.z)), g13 = gw_sc0(whu, widx(p1.w));
    float g20 = gw_sc0(whu, widx(p2.x)), g21 = gw_sc0(whu, widx(p2.y));
    float g22 = gw_sc0(whu, widx(p2.z)), g23 = gw_sc0(whu, widx(p2.w));
    float g30 = gw_sc0(whu, widx(p3.x)), g31 = gw_sc0(whu, widx(p3.y));
    float g32 = gw_sc0(whu, widx(p3.z)), g33 = gw_sc0(whu, widx(p3.w));
    float s0 = (fixw(p0.x, g00) + fixw(p0.y, g01)) + (fixw(p0.z, g02) + fixw(p0.w, g03));
    float s1 = (fixw(p1.x, g10) + fixw(p1.y, g11)) + (fixw(p1.z, g12) + fixw(p1.w, g13));
    float s2 = (fixw(p2.x, g20) + fixw(p2.y, g21)) + (fixw(p2.z, g22) + fixw(p2.w, g23));
    float s3 = (fixw(p3.x, g30) + fixw(p3.y, g31)) + (fixw(p3.z, g32) + fixw(p3.w, g33));
    y[i0] = (_Float16)s0;
    if (i1 < n) y[i1] = (_Float16)s1;
    if (i2 < n) y[i2] = (_Float16)s2;
    if (i3 < n) y[i3] = (_Float16)s3;
}

// partial stable LSE (no epsilon): -inf if all inputs -inf.
__device__ __forceinline__ float plse4(float a, float b, float c, float d) {
    float m = fmaxf(fmaxf(a, b), fmaxf(c, d));
    if (m == NEG_INF) return NEG_INF;
    float s = __expf(a - m) + __expf(b - m) + __expf(c - m) + __expf(d - m);
    return __logf(s) + m;
}

// exact two-way LSE merge (epsilon once, matching ref)
__device__ __forceinline__ float merge_lse(float LA, float LB) {
    float m = fmaxf(LA, LB);
    if (m == NEG_INF) return NEG_INF;
    float s = __expf(LA - m) + __expf(LB - m) + 1e-15f;
    return __logf(s) + m;
}

// Layer 1 (sum node): fused two-phase kernel, STRIDED 4 nodes/thread, partial
// LSE in registers across the block-level phase aligner.
// EXEC-PREDICATED gathers (round-7 lesson: address-clamping doubles the
// request count — masked-off lanes issue NO request, so each edge is
// gathered exactly once across the two phases). Plain y1 stores.
__global__ __launch_bounds__(256) void l1_fused_kernel(const _Float16* __restrict__ x,
                                                       const v4i* __restrict__ ptrs,
                                                       _Float16* __restrict__ y,
                                                       int n, int h, int half) {
    int t = blockIdx.x * blockDim.x + threadIdx.x;
    bool act = t < h;
    int tt = act ? t : 0;
    int i0 = tt, i1 = tt + h, i2 = tt + 2 * h, i3 = tt + 3 * h;
    int c1 = i1 < n ? i1 : 0, c2 = i2 < n ? i2 : 0, c3 = i3 < n ? i3 : 0;
    v4i p0 = __builtin_nontemporal_load(ptrs + i0);
    v4i p1 = __builtin_nontemporal_load(ptrs + c1);
    v4i p2 = __builtin_nontemporal_load(ptrs + c2);
    v4i p3 = __builtin_nontemporal_load(ptrs + c3);

    // phase A: lower-half working set (predicated — one request per edge)
    float a0 = NEG_INF, b0 = NEG_INF, e0 = NEG_INF, d0 = NEG_INF;
    float a1 = NEG_INF, b1 = NEG_INF, e1 = NEG_INF, d1 = NEG_INF;
    float a2 = NEG_INF, b2 = NEG_INF, e2 = NEG_INF, d2 = NEG_INF;
    float a3 = NEG_INF, b3 = NEG_INF, e3 = NEG_INF, d3 = NEG_INF;
    if (p0.x < half) a0 = (float)x[p0.x];
    if (p0.y < half) b0 = (float)x[p0.y];
    if (p0.z < half) e0 = (float)x[p0.z];
    if (p0.w < half) d0 = (float)x[p0.w];
    if (p1.x < half) a1 = (float)x[p1.x];
    if (p1.y < half) b1 = (float)x[p1.y];
    if (p1.z < half) e1 = (float)x[p1.z];
    if (p1.w < half) d1 = (float)x[p1.w];
    if (p2.x < half) a2 = (float)x[p2.x];
    if (p2.y < half) b2 = (float)x[p2.y];
    if (p2.z < half) e2 = (float)x[p2.z];
    if (p2.w < half) d2 = (float)x[p2.w];
    if (p3.x < half) a3 = (float)x[p3.x];
    if (p3.y < half) b3 = (float)x[p3.y];
    if (p3.z < half) e3 = (float)x[p3.z];
    if (p3.w < half) d3 = (float)x[p3.w];
    float la0 = plse4(a0, b0, e0, d0);
    float la1 = plse4(a1, b1, e1, d1);
    float la2 = plse4(a2, b2, e2, d2);
    float la3 = plse4(a3, b3, e3, d3);

    __syncthreads();  // phase aligner: co-resident waves keep working sets separated

    // phase B: upper-half working set + merge
    a0 = NEG_INF; b0 = NEG_INF; e0 = NEG_INF; d0 = NEG_INF;
    a1 = NEG_INF; b1 = NEG_INF; e1 = NEG_INF; d1 = NEG_INF;
    a2 = NEG_INF; b2 = NEG_INF; e2 = NEG_INF; d2 = NEG_INF;
    a3 = NEG_INF; b3 = NEG_INF; e3 = NEG_INF; d3 = NEG_INF;
    if (p0.x >= half) a0 = (float)x[p0.x];
    if (p0.y >= half) b0 = (float)x[p0.y];
    if (p0.z >= half) e0 = (float)x[p0.z];
    if (p0.w >= half) d0 = (float)x[p0.w];
    if (p1.x >= half) a1 = (float)x[p1.x];
    if (p1.y >= half) b1 = (float)x[p1.y];
    if (p1.z >= half) e1 = (float)x[p1.z];
    if (p1.w >= half) d1 = (float)x[p1.w];
    if (p2.x >= half) a2 = (float)x[p2.x];
    if (p2.y >= half) b2 = (float)x[p2.y];
    if (p2.z >= half) e2 = (float)x[p2.z];
    if (p2.w >= half) d2 = (float)x[p2.w];
    if (p3.x >= half) a3 = (float)x[p3.x];
    if (p3.y >= half) b3 = (float)x[p3.y];
    if (p3.z >= half) e3 = (float)x[p3.z];
    if (p3.w >= half) d3 = (float)x[p3.w];
    float s0 = merge_lse(la0, plse4(a0, b0, e0, d0));
    float s1 = merge_lse(la1, plse4(a1, b1, e1, d1));
    float s2 = merge_lse(la2, plse4(a2, b2, e2, d2));
    float s3 = merge_lse(la3, plse4(a3, b3, e3, d3));

    if (act) {
        y[i0] = (_Float16)s0;
        if (i1 < n) y[i1] = (_Float16)s1;
        if (i2 < n) y[i2] = (_Float16)s2;
        if (i3 < n) y[i3] = (_Float16)s3;
    }
}

// Product node (layer 2): STRIDED 2 nodes/thread. Plain stores to y2.
__global__ __launch_bounds__(256) void sum4_h2h_kernel(const _Float16* __restrict__ x,
                                                       const v4i* __restrict__ ptrs,
                                                       _Float16* __restrict__ y, int n, int h) {
    int t = blockIdx.x * blockDim.x + threadIdx.x;
    if (t >= h) return;
    int i0 = t, i1 = t + h;
    int c1 = i1 < n ? i1 : 0;
    v4i p0 = __builtin_nontemporal_load(ptrs + i0);
    v4i p1 = __builtin_nontemporal_load(ptrs + c1);
    float s0 = ((float)x[p0.x] + (float)x[p0.y]) + ((float)x[p0.z] + (float)x[p0.w]);
    float s1 = ((float)x[p1.x] + (float)x[p1.y]) + ((float)x[p1.z] + (float)x[p1.w]);
    y[i0] = (_Float16)s0;
    if (i1 < n) y[i1] = (_Float16)s1;
}

__device__ __forceinline__ float lse4(float a, float b, float c, float d) {
    float m = fmaxf(fmaxf(a, b), fmaxf(c, d));
    if (m == NEG_INF) return NEG_INF;
    float s = __expf(a - m) + __expf(b - m) + __expf(c - m) + __expf(d - m) + 1e-15f;
    return __logf(s) + m;
}

// Final sum node (layer 3): 1 node/thread. out has no GPU consumer -> nt store OK.
__global__ __launch_bounds__(256) void logsum4_h2f_kernel(const _Float16* __restrict__ x,
                                                          const v4i* __restrict__ ptrs,
                                                          float* __restrict__ y, int n) {
    int t = blockIdx.x * blockDim.x + threadIdx.x;
    if (t >= n) return;
    v4i p = __builtin_nontemporal_load(ptrs + t);
    float r = lse4((float)x[p.x], (float)x[p.y], (float)x[p.z], (float)x[p.w]);
    __builtin_nontemporal_store(r, y + t);
}

extern "C" void kernel_launch(void* const* d_in, const int* in_sizes, int n_in,
                              void* d_out, int out_size, void* d_ws, size_t ws_size,
                              hipStream_t stream) {
    // d_in dict order: weights, ptrs0, csr0, n0, ptrs1, csr1, n1, ptrs2, csr2, n2, ptrs3, csr3, n3
    const float* w     = (const float*)d_in[0];
    const v4i*   ptrs0 = (const v4i*)d_in[1];
    const v4i*   ptrs1 = (const v4i*)d_in[4];
    const v4i*   ptrs2 = (const v4i*)d_in[7];
    const v4i*   ptrs3 = (const v4i*)d_in[10];

    const int n_vars = in_sizes[0];
    const int n0 = in_sizes[1] / 4;
    const int n1 = in_sizes[4] / 4;
    const int n2 = in_sizes[7] / 4;
    const int n3 = in_sizes[10] / 4;

    // workspace layout (256B-aligned), intermediates fp16
    char* ws = (char*)d_ws;
    size_t off = 0;
    _Float16* wh = (_Float16*)(ws + off); off += ((size_t)n_vars * 2 + 255) & ~(size_t)255;
    _Float16* y0 = (_Float16*)(ws + off); off += ((size_t)n0 * 2 + 255) & ~(size_t)255;
    _Float16* y1 = (_Float16*)(ws + off); off += ((size_t)n1 * 2 + 255) & ~(size_t)255;
    _Float16* y2 = (_Float16*)(ws + off);
    float* out = (float*)d_out;

    const int B = 256;
    int hc = (n_vars + 3) / 4;
    int h0 = (n0 + 3) / 4;                 // enc: 4 nodes/thread
    int h1 = (n1 + 3) / 4;                 // l1 fused: 4 nodes/thread
    int h2 = (n2 + 1) / 2;                 // l2: 2 nodes/thread
    int half0 = n0 / 2;                    // 4 MB fp16 boundary of y0

    cvt_kernel        <<<(hc + B - 1) / B, B, 0, stream>>>(w, wh, n_vars);
    sum4_enc_kernel   <<<(h0 + B - 1) / B, B, 0, stream>>>(wh, ptrs0, y0, n0, h0);
    l1_fused_kernel   <<<(h1 + B - 1) / B, B, 0, stream>>>(y0, ptrs1, y1, n1, h1, half0);
    sum4_h2h_kernel   <<<(h2 + B - 1) / B, B, 0, stream>>>(y1, ptrs2, y2, n2, h2);
    logsum4_h2f_kernel<<<(n3 + B - 1) / B, B, 0, stream>>>(y2, ptrs3, out, n3);
}